// Round 1
// baseline (152.784 us; speedup 1.0000x reference)
//
#include <hip/hip_runtime.h>
#include <math.h>

#define NN 8192
#define DIM 128
#define TILE 128
#define BK 32
#define NT (NN / TILE)            // 64 tiles per dim
#define NBLK (NT * (NT + 1) / 2)  // 2080 upper-triangular blocks

// ---------------------------------------------------------------------------
// Kernel 1: per-row squared norms  sq[i] = ||mapping[i]||^2
// ---------------------------------------------------------------------------
__global__ void sq_kernel(const float* __restrict__ mapping, float* __restrict__ sq) {
    int i = blockIdx.x * blockDim.x + threadIdx.x;
    if (i < NN) {
        const float4* row = reinterpret_cast<const float4*>(mapping + (size_t)i * DIM);
        float s = 0.f;
#pragma unroll
        for (int q = 0; q < DIM / 4; ++q) {
            float4 v = row[q];
            s += v.x * v.x + v.y * v.y + v.z * v.z + v.w * v.w;
        }
        sq[i] = s;
    }
}

// ---------------------------------------------------------------------------
// Kernel 2: per-(128x128)-tile distance-distortion partial sums.
// Upper-triangular block set; off-diagonal blocks weighted x2 (D and d are
// symmetric). Register-blocked fp32 "GEMM" (gram) + fused epilogue.
// ---------------------------------------------------------------------------
__global__ __launch_bounds__(256, 4) void dist_kernel(const float* __restrict__ mapping,
                                                      const float* __restrict__ D,
                                                      const float* __restrict__ sq,
                                                      float* __restrict__ partials) {
    // Transposed tiles: As[k][row] so compute-side reads are contiguous float4s.
    __shared__ float As[BK][TILE];
    __shared__ float Bs[BK][TILE];

    // linear block -> (bi, bj) with bi <= bj
    int b = blockIdx.x;
    int bi = 0, rem = b, rowlen = NT;
    while (rem >= rowlen) { rem -= rowlen; ++bi; --rowlen; }
    int bj = bi + rem;

    const int t = threadIdx.x;
    const int tx = t & 15;   // 0..15 -> output cols tx*8..tx*8+7
    const int ty = t >> 4;   // 0..15 -> output rows ty*8..ty*8+7
    const int rowA0 = bi * TILE;
    const int rowB0 = bj * TILE;

    // staging mapping: 2 threads per row, 16 floats each
    const int srow = t >> 1;        // 0..127
    const int shalf = t & 1;        // 0 or 1

    float acc[8][8] = {};

    for (int k0 = 0; k0 < DIM; k0 += BK) {
#pragma unroll
        for (int q = 0; q < 4; ++q) {
            const int kk = shalf * 16 + q * 4;       // 0..28, step 4
            const int col = k0 + kk;
            float4 va = *reinterpret_cast<const float4*>(mapping + (size_t)(rowA0 + srow) * DIM + col);
            float4 vb = *reinterpret_cast<const float4*>(mapping + (size_t)(rowB0 + srow) * DIM + col);
            As[kk + 0][srow] = va.x; As[kk + 1][srow] = va.y;
            As[kk + 2][srow] = va.z; As[kk + 3][srow] = va.w;
            Bs[kk + 0][srow] = vb.x; Bs[kk + 1][srow] = vb.y;
            Bs[kk + 2][srow] = vb.z; Bs[kk + 3][srow] = vb.w;
        }
        __syncthreads();

#pragma unroll 4
        for (int kk = 0; kk < BK; ++kk) {
            float a[8], bb[8];
            *reinterpret_cast<float4*>(&a[0]) = *reinterpret_cast<const float4*>(&As[kk][ty * 8]);
            *reinterpret_cast<float4*>(&a[4]) = *reinterpret_cast<const float4*>(&As[kk][ty * 8 + 4]);
            *reinterpret_cast<float4*>(&bb[0]) = *reinterpret_cast<const float4*>(&Bs[kk][tx * 8]);
            *reinterpret_cast<float4*>(&bb[4]) = *reinterpret_cast<const float4*>(&Bs[kk][tx * 8 + 4]);
#pragma unroll
            for (int r = 0; r < 8; ++r)
#pragma unroll
                for (int c = 0; c < 8; ++c)
                    acc[r][c] = fmaf(a[r], bb[c], acc[r][c]);
        }
        __syncthreads();
    }

    // ---- epilogue: d2 -> d -> ratio, accumulate ----
    const int gi0 = rowA0 + ty * 8;
    const int gj0 = rowB0 + tx * 8;

    float sqa[8], sqb[8];
#pragma unroll
    for (int r = 0; r < 8; ++r) sqa[r] = sq[gi0 + r];
#pragma unroll
    for (int c = 0; c < 8; ++c) sqb[c] = sq[gj0 + c];

    float lsum = 0.f;
#pragma unroll
    for (int r = 0; r < 8; ++r) {
        const int gi = gi0 + r;
        const float* Drow = D + (size_t)gi * NN + gj0;
        float4 dv0 = *reinterpret_cast<const float4*>(Drow);
        float4 dv1 = *reinterpret_cast<const float4*>(Drow + 4);
        float Dv[8] = {dv0.x, dv0.y, dv0.z, dv0.w, dv1.x, dv1.y, dv1.z, dv1.w};
#pragma unroll
        for (int c = 0; c < 8; ++c) {
            const int gj = gj0 + c;
            float d2 = sqa[r] + sqb[c] - 2.f * acc[r][c];
            float d = (d2 > 0.f) ? sqrtf(d2) : 0.f;
            float den = Dv[c] + ((gi == gj) ? 1.f : 0.f);
            lsum += __fdividef(fabsf(d - Dv[c]), den);
        }
    }

    // off-diagonal block counts for both (i,j) and (j,i)
    if (bi != bj) lsum *= 2.f;

    // ---- deterministic block reduction ----
    for (int off = 32; off > 0; off >>= 1) lsum += __shfl_down(lsum, off, 64);

    __shared__ float wsum[4];
    if ((t & 63) == 0) wsum[t >> 6] = lsum;
    __syncthreads();
    if (t == 0) partials[b] = (wsum[0] + wsum[1]) + (wsum[2] + wsum[3]);
}

// ---------------------------------------------------------------------------
// Kernel 3: deterministic final reduction of block partials -> scalar
// ---------------------------------------------------------------------------
__global__ void reduce_kernel(const float* __restrict__ partials, float* __restrict__ out) {
    __shared__ double sm[256];
    const int t = threadIdx.x;
    double s = 0.0;
    for (int i = t; i < NBLK; i += 256) s += (double)partials[i];
    sm[t] = s;
    __syncthreads();
    for (int off = 128; off > 0; off >>= 1) {
        if (t < off) sm[t] += sm[t + off];
        __syncthreads();
    }
    if (t == 0) out[0] = (float)(sm[0] / ((double)NN * (double)NN - (double)NN));
}

// ---------------------------------------------------------------------------
extern "C" void kernel_launch(void* const* d_in, const int* in_sizes, int n_in,
                              void* d_out, int out_size, void* d_ws, size_t ws_size,
                              hipStream_t stream) {
    const float* mapping = (const float*)d_in[0];
    const float* D       = (const float*)d_in[1];
    float* out = (float*)d_out;

    float* sq       = (float*)d_ws;   // NN floats
    float* partials = sq + NN;        // NBLK floats

    sq_kernel<<<(NN + 255) / 256, 256, 0, stream>>>(mapping, sq);
    dist_kernel<<<NBLK, 256, 0, stream>>>(mapping, D, sq, partials);
    reduce_kernel<<<1, 256, 0, stream>>>(partials, out);
}

// Round 2
// 109.815 us; speedup vs baseline: 1.3913x; 1.3913x over previous
//
#include <hip/hip_runtime.h>
#include <math.h>

#define NN 8192
#define DIM 128
#define TILE 128
#define NT (NN / TILE)            // 64
#define NBLK (NT * (NT + 1) / 2)  // 2080

typedef short bf16x8 __attribute__((ext_vector_type(8)));
typedef float f32x4 __attribute__((ext_vector_type(4)));

__device__ inline void gload_lds16(const void* g, void* l) {
    __builtin_amdgcn_global_load_lds((const __attribute__((address_space(1))) void*)g,
                                     (__attribute__((address_space(3))) void*)l, 16, 0, 0);
}

__device__ inline unsigned short f2bf(float x) {
    unsigned u = __float_as_uint(x);
    unsigned r = u + 0x7FFFu + ((u >> 16) & 1u);  // round-to-nearest-even
    return (unsigned short)(r >> 16);
}
__device__ inline float bf2f(unsigned short h) {
    return __uint_as_float(((unsigned)h) << 16);
}

// ---------------------------------------------------------------------------
// Kernel 0: fp32 -> (hi, lo) bf16 split.  buf[0][N][DIM]=hi, buf[1][N][DIM]=lo
// ---------------------------------------------------------------------------
__global__ void convert_kernel(const float* __restrict__ m, unsigned short* __restrict__ buf) {
    int i = (blockIdx.x * 256 + threadIdx.x) * 4;
    float4 v = *reinterpret_cast<const float4*>(m + i);
    float f[4] = {v.x, v.y, v.z, v.w};
    ushort4 hv, lv;
    unsigned short* hp = (unsigned short*)&hv;
    unsigned short* lp = (unsigned short*)&lv;
#pragma unroll
    for (int q = 0; q < 4; ++q) {
        unsigned short h = f2bf(f[q]);
        hp[q] = h;
        lp[q] = f2bf(f[q] - bf2f(h));
    }
    *reinterpret_cast<ushort4*>(buf + i) = hv;
    *reinterpret_cast<ushort4*>(buf + NN * DIM + i) = lv;
}

// ---------------------------------------------------------------------------
// Kernel 1: per-row squared norms from ORIGINAL fp32 (exact)
// ---------------------------------------------------------------------------
__global__ void sq_kernel(const float* __restrict__ mapping, float* __restrict__ sq) {
    int i = blockIdx.x * blockDim.x + threadIdx.x;
    if (i < NN) {
        const float4* row = reinterpret_cast<const float4*>(mapping + (size_t)i * DIM);
        float s = 0.f;
#pragma unroll
        for (int q = 0; q < DIM / 4; ++q) {
            float4 v = row[q];
            s += v.x * v.x + v.y * v.y + v.z * v.z + v.w * v.w;
        }
        sq[i] = s;
    }
}

// ---------------------------------------------------------------------------
// Kernel 2: 128x128 tile: split-bf16 MFMA gram + fused distortion epilogue.
// LDS layout = MFMA fragment order: chunk c (1KB) holds, for 64 lanes, 16B
// each at c*1024 + lane*16 — global_load_lds-linear AND conflict-free reads.
// chunk id: side(A=0,B=1)*32 + (tile16*2 + kstep)*2 + split(h=0,l=1)
// ---------------------------------------------------------------------------
__global__ __launch_bounds__(256, 2) void dist_kernel(const unsigned short* __restrict__ buf,
                                                      const float* __restrict__ D,
                                                      const float* __restrict__ sq,
                                                      float* __restrict__ partials) {
    __shared__ unsigned short lds[32768];  // 64 KiB

    int b = blockIdx.x;
    int bi = 0, rem = b, rowlen = NT;
    while (rem >= rowlen) { rem -= rowlen; ++bi; --rowlen; }
    int bj = bi + rem;
    const int rowA0 = bi * TILE, rowB0 = bj * TILE;

    const int t = threadIdx.x;
    const int lane = t & 63;
    const int w = t >> 6;
    const int wr = w >> 1, wc = w & 1;

    // staging role: wave w stages side=(w>>1) (A/B), split h=(w&1), 16 chunks
    const int side = w >> 1, h = w & 1;
    const int stage_rows0 = side ? rowB0 : rowA0;
    const int off_lane = (lane & 15) * DIM + (lane >> 4) * 8;  // elements
    const unsigned short* gsrc0 =
        buf + (size_t)h * (NN * DIM) + (size_t)stage_rows0 * DIM + off_lane;

    f32x4 acc[4][4] = {};

#pragma unroll
    for (int s = 0; s < 2; ++s) {
        // ---- stage 16 chunks (global -> LDS, fragment order) ----
        const unsigned short* gs = gsrc0 + s * 64;
#pragma unroll
        for (int tt = 0; tt < 8; ++tt)
#pragma unroll
            for (int q = 0; q < 2; ++q) {
                int chunk = side * 32 + (tt * 2 + q) * 2 + h;
                gload_lds16(gs + tt * 16 * DIM + q * 32, (void*)&lds[chunk * 512]);
            }
        __syncthreads();

        // ---- compute: 2 k-steps of K=32 ----
#pragma unroll
        for (int q = 0; q < 2; ++q) {
            bf16x8 ah[4], al[4], bh[4], bl[4];
#pragma unroll
            for (int i = 0; i < 4; ++i) {
                int at = wr * 4 + i, bt = wc * 4 + i;
                ah[i] = *(const bf16x8*)&lds[((at * 2 + q) * 2 + 0) * 512 + lane * 8];
                al[i] = *(const bf16x8*)&lds[((at * 2 + q) * 2 + 1) * 512 + lane * 8];
                bh[i] = *(const bf16x8*)&lds[(32 + (bt * 2 + q) * 2 + 0) * 512 + lane * 8];
                bl[i] = *(const bf16x8*)&lds[(32 + (bt * 2 + q) * 2 + 1) * 512 + lane * 8];
            }
#pragma unroll
            for (int i = 0; i < 4; ++i)
#pragma unroll
                for (int j = 0; j < 4; ++j) {
                    acc[i][j] = __builtin_amdgcn_mfma_f32_16x16x32_bf16(ah[i], bh[j], acc[i][j], 0, 0, 0);
                    acc[i][j] = __builtin_amdgcn_mfma_f32_16x16x32_bf16(ah[i], bl[j], acc[i][j], 0, 0, 0);
                    acc[i][j] = __builtin_amdgcn_mfma_f32_16x16x32_bf16(al[i], bh[j], acc[i][j], 0, 0, 0);
                }
        }
        __syncthreads();
    }

    // ---- epilogue: C/D layout col=lane&15, row=(lane>>4)*4+reg ----
    const int gi_base = rowA0 + wr * 64 + (lane >> 4) * 4;  // + i*16 + reg
    const int gj_base = rowB0 + wc * 64 + (lane & 15);      // + j*16
    float lsum = 0.f;
#pragma unroll
    for (int i = 0; i < 4; ++i) {
        float sqa[4];
#pragma unroll
        for (int r = 0; r < 4; ++r) sqa[r] = sq[gi_base + i * 16 + r];
#pragma unroll
        for (int j = 0; j < 4; ++j) {
            const int gj = gj_base + j * 16;
            const float sqb = sq[gj];
            const float* Dp = D + (size_t)(gi_base + i * 16) * NN + gj;
#pragma unroll
            for (int r = 0; r < 4; ++r) {
                const int gi = gi_base + i * 16 + r;
                float Dv = Dp[(size_t)r * NN];
                float d2 = sqa[r] + sqb - 2.f * acc[i][j][r];
                float d = d2 > 0.f ? sqrtf(d2) : 0.f;
                if (gi != gj) lsum += __fdividef(fabsf(d - Dv), Dv);
            }
        }
    }
    if (bi != bj) lsum *= 2.f;

    // deterministic block reduction
    for (int off = 32; off > 0; off >>= 1) lsum += __shfl_down(lsum, off, 64);
    __shared__ float wsum[4];
    if (lane == 0) wsum[w] = lsum;
    __syncthreads();
    if (t == 0) partials[b] = (wsum[0] + wsum[1]) + (wsum[2] + wsum[3]);
}

// ---------------------------------------------------------------------------
// Kernel 3: deterministic final reduction
// ---------------------------------------------------------------------------
__global__ void reduce_kernel(const float* __restrict__ partials, float* __restrict__ out) {
    __shared__ double sm[256];
    const int t = threadIdx.x;
    double s = 0.0;
    for (int i = t; i < NBLK; i += 256) s += (double)partials[i];
    sm[t] = s;
    __syncthreads();
    for (int off = 128; off > 0; off >>= 1) {
        if (t < off) sm[t] += sm[t + off];
        __syncthreads();
    }
    if (t == 0) out[0] = (float)(sm[0] / ((double)NN * (double)NN - (double)NN));
}

// ---------------------------------------------------------------------------
extern "C" void kernel_launch(void* const* d_in, const int* in_sizes, int n_in,
                              void* d_out, int out_size, void* d_ws, size_t ws_size,
                              hipStream_t stream) {
    const float* mapping = (const float*)d_in[0];
    const float* D       = (const float*)d_in[1];
    float* out = (float*)d_out;

    unsigned short* buf = (unsigned short*)d_ws;            // 2 * NN * DIM bf16 = 4 MiB
    float* sq           = (float*)(buf + 2 * NN * DIM);     // NN floats
    float* partials     = sq + NN;                          // NBLK floats

    convert_kernel<<<(NN * DIM) / 1024, 256, 0, stream>>>(mapping, buf);
    sq_kernel<<<NN / 256, 256, 0, stream>>>(mapping, sq);
    dist_kernel<<<NBLK, 256, 0, stream>>>(buf, D, sq, partials);
    reduce_kernel<<<1, 256, 0, stream>>>(partials, out);
}

// Round 3
// 94.677 us; speedup vs baseline: 1.6137x; 1.1599x over previous
//
#include <hip/hip_runtime.h>
#include <math.h>

#define NN 8192
#define DIM 128
#define TILE 128
#define NT (NN / TILE)            // 64
#define NBLK (NT * (NT + 1) / 2)  // 2080

typedef short bf16x8 __attribute__((ext_vector_type(8)));
typedef float f32x4 __attribute__((ext_vector_type(4)));

__device__ inline void gload_lds16(const void* g, void* l) {
    __builtin_amdgcn_global_load_lds((const __attribute__((address_space(1))) void*)g,
                                     (__attribute__((address_space(3))) void*)l, 16, 0, 0);
}

__device__ inline unsigned short f2bf(float x) {
    unsigned u = __float_as_uint(x);
    unsigned r = u + 0x7FFFu + ((u >> 16) & 1u);  // round-to-nearest-even
    return (unsigned short)(r >> 16);
}
__device__ inline float bf2f(unsigned short h) {
    return __uint_as_float(((unsigned)h) << 16);
}

// ---------------------------------------------------------------------------
// Kernel 0: fp32 -> (hi, lo) bf16 split.  buf[0][N][DIM]=hi, buf[1][N][DIM]=lo
// ---------------------------------------------------------------------------
__global__ void convert_kernel(const float* __restrict__ m, unsigned short* __restrict__ buf) {
    int i = (blockIdx.x * 256 + threadIdx.x) * 4;
    float4 v = *reinterpret_cast<const float4*>(m + i);
    float f[4] = {v.x, v.y, v.z, v.w};
    ushort4 hv, lv;
    unsigned short* hp = (unsigned short*)&hv;
    unsigned short* lp = (unsigned short*)&lv;
#pragma unroll
    for (int q = 0; q < 4; ++q) {
        unsigned short h = f2bf(f[q]);
        hp[q] = h;
        lp[q] = f2bf(f[q] - bf2f(h));
    }
    *reinterpret_cast<ushort4*>(buf + i) = hv;
    *reinterpret_cast<ushort4*>(buf + NN * DIM + i) = lv;
}

// ---------------------------------------------------------------------------
// Kernel 1: per-row squared norms from ORIGINAL fp32 (exact)
// ---------------------------------------------------------------------------
__global__ void sq_kernel(const float* __restrict__ mapping, float* __restrict__ sq) {
    int i = blockIdx.x * blockDim.x + threadIdx.x;
    if (i < NN) {
        const float4* row = reinterpret_cast<const float4*>(mapping + (size_t)i * DIM);
        float s = 0.f;
#pragma unroll
        for (int q = 0; q < DIM / 4; ++q) {
            float4 v = row[q];
            s += v.x * v.x + v.y * v.y + v.z * v.z + v.w * v.w;
        }
        sq[i] = s;
    }
}

// ---------------------------------------------------------------------------
// Kernel 2: 128x128 tile, split-bf16 MFMA gram + fused distortion epilogue.
// KEY CHANGES vs r2:
//   (a) D tile prefetched into registers as float4 at block START (before any
//       barrier) -> ~128 KB/CU in flight, latency paid once, overlapped.
//   (b) MFMA operands SWAPPED (mfma(bfrag, afrag)) so acc reg index r walks
//       the B-side row => lane's 4 acc elements pair with 4 consecutive D
//       columns => D loads are aligned dwordx4.
// acc[i][j][r] = G[a][b0+r], a = rowA0+wr*64+i*16+(lane&15),
//                            b0 = rowB0+wc*64+j*16+(lane>>4)*4
// ---------------------------------------------------------------------------
__global__ __launch_bounds__(256, 2) void dist_kernel(const unsigned short* __restrict__ buf,
                                                      const float* __restrict__ D,
                                                      const float* __restrict__ sq,
                                                      float* __restrict__ partials) {
    __shared__ unsigned short lds[32768];  // 64 KiB

    int b = blockIdx.x;
    int bi = 0, rem = b, rowlen = NT;
    while (rem >= rowlen) { rem -= rowlen; ++bi; --rowlen; }
    int bj = bi + rem;
    const int rowA0 = bi * TILE, rowB0 = bj * TILE;

    const int t = threadIdx.x;
    const int lane = t & 63;
    const int w = t >> 6;
    const int wr = w >> 1, wc = w & 1;

    // ---- D + sq prefetch (issued before any barrier; drained at 1st sync) ----
    const int abase = rowA0 + wr * 64 + (lane & 15);   // + i*16
    const int bbase = rowB0 + wc * 64 + (lane >> 4) * 4;  // + j*16 (+r)
    float4 dreg[4][4];
    float sqa4[4];
    float4 sqb4[4];
#pragma unroll
    for (int i = 0; i < 4; ++i) {
        sqa4[i] = sq[abase + i * 16];
#pragma unroll
        for (int j = 0; j < 4; ++j)
            dreg[i][j] = *reinterpret_cast<const float4*>(
                D + (size_t)(abase + i * 16) * NN + (bbase + j * 16));
    }
#pragma unroll
    for (int j = 0; j < 4; ++j)
        sqb4[j] = *reinterpret_cast<const float4*>(sq + bbase + j * 16);

    // staging role: wave w stages side=(w>>1) (A/B), split h=(w&1), 16 chunks
    const int side = w >> 1, h = w & 1;
    const int stage_rows0 = side ? rowB0 : rowA0;
    const int off_lane = (lane & 15) * DIM + (lane >> 4) * 8;  // elements
    const unsigned short* gsrc0 =
        buf + (size_t)h * (NN * DIM) + (size_t)stage_rows0 * DIM + off_lane;

    f32x4 acc[4][4] = {};

#pragma unroll
    for (int s = 0; s < 2; ++s) {
        const unsigned short* gs = gsrc0 + s * 64;
#pragma unroll
        for (int tt = 0; tt < 8; ++tt)
#pragma unroll
            for (int q = 0; q < 2; ++q) {
                int chunk = side * 32 + (tt * 2 + q) * 2 + h;
                gload_lds16(gs + tt * 16 * DIM + q * 32, (void*)&lds[chunk * 512]);
            }
        __syncthreads();

#pragma unroll
        for (int q = 0; q < 2; ++q) {
            bf16x8 ah[4], al[4], bh[4], bl[4];
#pragma unroll
            for (int i = 0; i < 4; ++i) {
                int at = wr * 4 + i, bt = wc * 4 + i;
                ah[i] = *(const bf16x8*)&lds[((at * 2 + q) * 2 + 0) * 512 + lane * 8];
                al[i] = *(const bf16x8*)&lds[((at * 2 + q) * 2 + 1) * 512 + lane * 8];
                bh[i] = *(const bf16x8*)&lds[(32 + (bt * 2 + q) * 2 + 0) * 512 + lane * 8];
                bl[i] = *(const bf16x8*)&lds[(32 + (bt * 2 + q) * 2 + 1) * 512 + lane * 8];
            }
            // swapped operands: result row walks B-side rows (reg r), col = A row
#pragma unroll
            for (int i = 0; i < 4; ++i)
#pragma unroll
                for (int j = 0; j < 4; ++j) {
                    acc[i][j] = __builtin_amdgcn_mfma_f32_16x16x32_bf16(bh[j], ah[i], acc[i][j], 0, 0, 0);
                    acc[i][j] = __builtin_amdgcn_mfma_f32_16x16x32_bf16(bl[j], ah[i], acc[i][j], 0, 0, 0);
                    acc[i][j] = __builtin_amdgcn_mfma_f32_16x16x32_bf16(bh[j], al[i], acc[i][j], 0, 0, 0);
                }
        }
        __syncthreads();
    }

    // ---- epilogue: all D/sq already in registers ----
    float lsum = 0.f;
#pragma unroll
    for (int i = 0; i < 4; ++i) {
        const int a = abase + i * 16;
        const float sa = sqa4[i];
#pragma unroll
        for (int j = 0; j < 4; ++j) {
            const int b0 = bbase + j * 16;
            const float4 Dv = dreg[i][j];
            const float Dvr[4] = {Dv.x, Dv.y, Dv.z, Dv.w};
            const float sbv[4] = {sqb4[j].x, sqb4[j].y, sqb4[j].z, sqb4[j].w};
#pragma unroll
            for (int r = 0; r < 4; ++r) {
                float d2 = sa + sbv[r] - 2.f * acc[i][j][r];
                float d = d2 > 0.f ? sqrtf(d2) : 0.f;
                if (a != b0 + r) lsum += __fdividef(fabsf(d - Dvr[r]), Dvr[r]);
            }
        }
    }
    if (bi != bj) lsum *= 2.f;

    // deterministic block reduction
    for (int off = 32; off > 0; off >>= 1) lsum += __shfl_down(lsum, off, 64);
    __shared__ float wsum[4];
    if (lane == 0) wsum[w] = lsum;
    __syncthreads();
    if (t == 0) partials[b] = (wsum[0] + wsum[1]) + (wsum[2] + wsum[3]);
}

// ---------------------------------------------------------------------------
// Kernel 3: deterministic final reduction
// ---------------------------------------------------------------------------
__global__ void reduce_kernel(const float* __restrict__ partials, float* __restrict__ out) {
    __shared__ double sm[256];
    const int t = threadIdx.x;
    double s = 0.0;
    for (int i = t; i < NBLK; i += 256) s += (double)partials[i];
    sm[t] = s;
    __syncthreads();
    for (int off = 128; off > 0; off >>= 1) {
        if (t < off) sm[t] += sm[t + off];
        __syncthreads();
    }
    if (t == 0) out[0] = (float)(sm[0] / ((double)NN * (double)NN - (double)NN));
}

// ---------------------------------------------------------------------------
extern "C" void kernel_launch(void* const* d_in, const int* in_sizes, int n_in,
                              void* d_out, int out_size, void* d_ws, size_t ws_size,
                              hipStream_t stream) {
    const float* mapping = (const float*)d_in[0];
    const float* D       = (const float*)d_in[1];
    float* out = (float*)d_out;

    unsigned short* buf = (unsigned short*)d_ws;            // 2 * NN * DIM bf16 = 4 MiB
    float* sq           = (float*)(buf + 2 * NN * DIM);     // NN floats
    float* partials     = sq + NN;                          // NBLK floats

    convert_kernel<<<(NN * DIM) / 1024, 256, 0, stream>>>(mapping, buf);
    sq_kernel<<<NN / 256, 256, 0, stream>>>(mapping, sq);
    dist_kernel<<<NBLK, 256, 0, stream>>>(buf, D, sq, partials);
    reduce_kernel<<<1, 256, 0, stream>>>(partials, out);
}